// Round 6
// baseline (346.617 us; speedup 1.0000x reference)
//
#include <hip/hip_runtime.h>
#include <stdint.h>
#include <math.h>

#define NN 2048
#define BB 8
#define BN (BB*NN)
#define KK 16
#define EE (BN*KK)
#define HID 128
#define PROJ_D 256
#define QPB 16   // queries (waves) per knn block

typedef unsigned long long u64;

__device__ __forceinline__ u64 wave_min_u64(u64 v) {
  #pragma unroll
  for (int off = 32; off > 0; off >>= 1) {
    u64 o = __shfl_xor(v, off);
    v = o < v ? o : v;
  }
  return v;
}

// ---------------- kNN: 16 waves per block, one query per wave ----------------
// Exact histogram selection, thresholded: only candidates with bin<256 under
// scale=1024 (d<0.25) are histogrammed (~134 of 2048 expected; 17th-NN radius
// ~0.126).  If a wave sees <17 such candidates, rescale 1024->256 (covers all
// d<=0.87) -- still exact.  Hist is wave-private: no cross-wave sync needed.
// key = (dist_bits << 11) | j reproduces top_k tie-break exactly.
__global__ __launch_bounds__(1024) void knn_kernel(const float* __restrict__ pos,
                                                   int* __restrict__ nbr) {
  __shared__ float4 Ps[NN];            // 32 KB
  __shared__ unsigned Hist[QPB * 256]; // 16 KB, private 256 bins per wave
  const int b  = blockIdx.x >> 7;          // / (NN/QPB) = /128
  const int qb = blockIdx.x & 127;
  const int wave = threadIdx.x >> 6;
  const int lane = threadIdx.x & 63;
  const int i = qb * QPB + wave;           // query index within batch
  const float* P = pos + (size_t)b * NN * 3;

  for (int t = threadIdx.x; t < NN; t += 1024)
    Ps[t] = make_float4(P[t*3], P[t*3+1], P[t*3+2], 0.f);
  __syncthreads();   // Ps staged; everything below is wave-local

  const float4 pi = Ps[i];
  const float xi = pi.x, yi = pi.y, zi = pi.z;
  unsigned* H = &Hist[wave * 256];

  // ---- pass 1: distances (exact reference arithmetic) ----
  float d[32];
  #pragma unroll
  for (int t = 0; t < 32; t++) {
    int j = t * 64 + lane;
    float4 pj = Ps[j];
    // min-image: min(|Δ|, 1-|Δ|) == where(|Δ|>0.5, 1-|Δ|, |Δ|) exactly
    float ax = fabsf(xi - pj.x), ay = fabsf(yi - pj.y), az = fabsf(zi - pj.z);
    float dx = fminf(ax, 1.0f - ax);
    float dy = fminf(ay, 1.0f - ay);
    float dz = fminf(az, 1.0f - az);
    // match numpy fp32 exactly: no FMA contraction, sum order ((x+y)+z)+eps
    float s = __fadd_rn(__fadd_rn(__fadd_rn(__fmul_rn(dx,dx), __fmul_rn(dy,dy)),
                                  __fmul_rn(dz,dz)), 1e-12f);
    d[t] = __fsqrt_rn(s);
  }

  // ---- histogram + rank-17 bin search (wave-local; rescale fallback) ----
  float scale = 1024.0f;
  int bstar = 0; unsigned C = 0;
  for (;;) {
    *(uint4*)&H[lane * 4] = make_uint4(0u, 0u, 0u, 0u);
    #pragma unroll
    for (int t = 0; t < 32; t++) {
      int bin = (int)(d[t] * scale);
      if (bin < 256) atomicAdd(&H[bin], 1u);
    }
    uint4 cv = *(const uint4*)&H[lane * 4];
    unsigned s4 = cv.x + cv.y + cv.z + cv.w;
    unsigned incl = s4;
    #pragma unroll
    for (int off = 1; off < 64; off <<= 1) {
      unsigned v = __shfl_up(incl, off);
      if (lane >= off) incl += v;
    }
    unsigned total = __shfl(incl, 63);
    if (total >= 17u) {
      unsigned base = incl - s4;
      bool has = (incl >= 17u) && (base < 17u);   // exactly one lane
      u64 hmask = __ballot(has);
      int srcl = __ffsll((unsigned long long)hmask) - 1;
      int bl = 0; unsigned Cl = 0;
      if (has) {
        if (base + cv.x >= 17u)                    { bl = lane*4 + 0; Cl = base; }
        else if (base + cv.x + cv.y >= 17u)        { bl = lane*4 + 1; Cl = base + cv.x; }
        else if (base + cv.x + cv.y + cv.z >= 17u) { bl = lane*4 + 2; Cl = base + cv.x + cv.y; }
        else                                       { bl = lane*4 + 3; Cl = base + cv.x + cv.y + cv.z; }
      }
      bstar = __shfl(bl, srcl);
      C     = __shfl(Cl, srcl);
      break;
    }
    scale *= 0.25f;   // 1024 -> 256: covers all d (<0.87 -> bin<223), total=2048
  }
  const int m = 17 - (int)C;                   // 1..17 members needed from bstar

  // ---- per-lane sorted list (6 slots) of this lane's members of bin bstar ----
  u64 lst[6];
  #pragma unroll
  for (int t = 0; t < 6; t++) lst[t] = ~0ull;
  #pragma unroll
  for (int t = 0; t < 32; t++) {
    int bin = (int)(d[t] * scale);
    u64 key = ((u64)__float_as_uint(d[t]) << 11) | (unsigned)(t * 64 + lane);
    u64 cand = (bin == bstar) ? key : ~0ull;
    if (cand < lst[5]) {
      lst[5] = cand;
      #pragma unroll
      for (int u = 5; u > 0; u--) {
        u64 a = lst[u-1], c2 = lst[u];
        lst[u-1] = a < c2 ? a : c2;
        lst[u]   = a < c2 ? c2 : a;
      }
    }
  }

  // ---- extract m smallest keys within bin bstar; kstar = 17th overall ----
  u64 kstar = 0;
  #pragma unroll 1
  for (int r = 0; r < m; r++) {
    u64 h0 = lst[0];
    u64 gm = wave_min_u64(h0);
    kstar = gm;
    bool win = (h0 == gm);
    #pragma unroll
    for (int u = 0; u < 5; u++) lst[u] = win ? lst[u+1] : lst[u];
    lst[5] = win ? ~0ull : lst[5];
  }

  // ---- emission: all keys <= kstar, excluding self; ballot compaction ----
  int* outp = nbr + ((size_t)b * NN + i) * KK;
  int total = 0;
  #pragma unroll
  for (int t = 0; t < 32; t++) {
    int j = t * 64 + lane;
    u64 key = ((u64)__float_as_uint(d[t]) << 11) | (unsigned)j;
    bool pred = (key <= kstar) && (j != i);
    u64 msk = __ballot(pred);
    if (pred) {
      int ofs = total + __popcll(msk & ((1ull << lane) - 1ull));
      outp[ofs] = b * NN + j;
    }
    total += __popcll(msk);
  }
}

// ---------------- CSR build ----------------
__global__ __launch_bounds__(256) void count_kernel(const int* __restrict__ nbr,
                                                    int* __restrict__ cnt) {
  int e = blockIdx.x * 256 + threadIdx.x;
  atomicAdd(&cnt[nbr[e]], 1);
}

__global__ __launch_bounds__(256) void scan_kernel(const int* __restrict__ cnt,
                                                   int* __restrict__ row_ptr) {
  __shared__ int ps[256];
  int t = threadIdx.x;
  const int4* cv = (const int4*)(cnt + t * 64);
  int4 c[16];
  int s = 0;
  #pragma unroll
  for (int i = 0; i < 16; i++) {
    c[i] = cv[i];
    s += c[i].x + c[i].y + c[i].z + c[i].w;
  }
  ps[t] = s;
  __syncthreads();
  for (int off = 1; off < 256; off <<= 1) {
    int v = 0;
    if (t >= off) v = ps[t - off];
    __syncthreads();
    ps[t] += v;
    __syncthreads();
  }
  int run = t ? ps[t - 1] : 0;
  int4* rp = (int4*)(row_ptr + t * 64);
  #pragma unroll
  for (int i = 0; i < 16; i++) {
    int4 o;
    o.x = run; run += c[i].x;
    o.y = run; run += c[i].y;
    o.z = run; run += c[i].z;
    o.w = run; run += c[i].w;
    rp[i] = o;
  }
  if (t == 255) row_ptr[BN] = run;
}

__global__ __launch_bounds__(256) void fill_kernel(const int* __restrict__ nbr,
                                                   const int* __restrict__ row_ptr,
                                                   int* __restrict__ fill,
                                                   int* __restrict__ col) {
  int e = blockIdx.x * 256 + threadIdx.x;
  int d = nbr[e];
  int srcn = e >> 4;                  // / KK
  int p = row_ptr[d] + atomicAdd(&fill[d], 1);
  col[p] = srcn;
}

// ---------------- encoder layer 0: (BN,5)@(5,128)+relu ----------------
__global__ __launch_bounds__(256) void enc0_kernel(const float* __restrict__ x,
                                                   const float* __restrict__ w0,
                                                   const float* __restrict__ b0,
                                                   float* __restrict__ h) {
  int t = blockIdx.x * 256 + threadIdx.x;
  int m = t >> 5;
  int c = (t & 31) * 4;
  float xv[5];
  #pragma unroll
  for (int d = 0; d < 5; d++) xv[d] = x[m * 5 + d];
  float4 acc = *(const float4*)&b0[c];
  #pragma unroll
  for (int d = 0; d < 5; d++) {
    float4 w = *(const float4*)&w0[d * HID + c];
    acc.x += xv[d] * w.x; acc.y += xv[d] * w.y;
    acc.z += xv[d] * w.z; acc.w += xv[d] * w.w;
  }
  acc.x = fmaxf(acc.x, 0.f); acc.y = fmaxf(acc.y, 0.f);
  acc.z = fmaxf(acc.z, 0.f); acc.w = fmaxf(acc.w, 0.f);
  *(float4*)&h[(size_t)m * HID + c] = acc;
}

// ---------------- W-in-LDS GEMM, 64-row tiles, 8 rows/thread ---------------
// Round-5 diagnosis: 4-row/thread inner loop was LDS-throughput-bound
// (~96 LDS cyc per 128 VALU cyc per wave, LDS shared CU-wide).  8 rows/thread
// halves W-read cost per FMA; A reads are same-address broadcasts (free-ish).
// LDS = 64K (Ws) + 32K (As) = 96 KB -> 1 block/CU, 8 waves (2/SIMD); VGPR
// headroom to 256 is free at this occupancy.
template<int TWOPH, int RELU, int HASRES>
__device__ __forceinline__ void gemm_body(
    const float* __restrict__ A1, const float* __restrict__ W1,
    const float* __restrict__ A2, const float* __restrict__ W2,
    const float* __restrict__ bias, const float* __restrict__ Res,
    float* __restrict__ out, int ldW, int ldOut, int m0, int n0,
    float* Ws, float* As) {
  const int tid = threadIdx.x;
  const int tx = tid & 31, ty = tid >> 5;     // tx: 4-col group, ty: 0..7

  float acc[8][4];
  #pragma unroll
  for (int r = 0; r < 8; r++)
    #pragma unroll
    for (int j = 0; j < 4; j++) acc[r][j] = 0.f;

  #pragma unroll 1
  for (int ph = 0; ph < (TWOPH ? 2 : 1); ph++) {
    const float* Ap = ph ? A2 : A1;
    const float* Wp = ph ? W2 : W1;
    if (ph) __syncthreads();           // all reads of Ws/As from phase 0 done
    // stage W tile [128 x 128] (cols n0..n0+127, row stride ldW)
    {
      int row = tid >> 5, c4 = tid & 31;
      #pragma unroll
      for (int it = 0; it < 16; it++) {
        ((float4*)Ws)[tid + it * 256] =
            *(const float4*)&Wp[(size_t)(row + it * 8) * ldW + n0 + c4 * 4];
      }
    }
    // stage A tile [64 x 128]
    {
      const float4* Apv = (const float4*)(Ap + (size_t)m0 * 128);
      #pragma unroll
      for (int it = 0; it < 8; it++)
        ((float4*)As)[tid + it * 256] = Apv[tid + it * 256];
    }
    __syncthreads();

    #pragma unroll 4
    for (int k4 = 0; k4 < 32; k4++) {
      float4 w0 = ((const float4*)Ws)[(k4 * 4 + 0) * 32 + tx];
      float4 w1 = ((const float4*)Ws)[(k4 * 4 + 1) * 32 + tx];
      float4 w2 = ((const float4*)Ws)[(k4 * 4 + 2) * 32 + tx];
      float4 w3 = ((const float4*)Ws)[(k4 * 4 + 3) * 32 + tx];
      #pragma unroll
      for (int r = 0; r < 8; r++) {
        float4 a = ((const float4*)As)[(ty + r * 8) * 32 + k4];
        acc[r][0] += a.x*w0.x + a.y*w1.x + a.z*w2.x + a.w*w3.x;
        acc[r][1] += a.x*w0.y + a.y*w1.y + a.z*w2.y + a.w*w3.y;
        acc[r][2] += a.x*w0.z + a.y*w1.z + a.z*w2.z + a.w*w3.z;
        acc[r][3] += a.x*w0.w + a.y*w1.w + a.z*w2.w + a.w*w3.w;
      }
    }
  }

  const int n = n0 + tx * 4;
  float4 bv = make_float4(0.f, 0.f, 0.f, 0.f);
  if (bias) bv = *(const float4*)&bias[n];
  #pragma unroll
  for (int r = 0; r < 8; r++) {
    int m = m0 + ty + r * 8;
    float4 o;
    o.x = acc[r][0] + bv.x; o.y = acc[r][1] + bv.y;
    o.z = acc[r][2] + bv.z; o.w = acc[r][3] + bv.w;
    if (RELU) {
      o.x = fmaxf(o.x, 0.f); o.y = fmaxf(o.y, 0.f);
      o.z = fmaxf(o.z, 0.f); o.w = fmaxf(o.w, 0.f);
    }
    if (HASRES) {
      float4 rr = *(const float4*)&Res[(size_t)m * ldOut + n];
      o.x += rr.x; o.y += rr.y; o.z += rr.z; o.w += rr.w;
    }
    *(float4*)&out[(size_t)m * ldOut + n] = o;
  }
}

template<int TWOPH, int RELU, int HASRES>
__global__ __launch_bounds__(256) void gemmW(
    const float* __restrict__ A1, const float* __restrict__ W1,
    const float* __restrict__ A2, const float* __restrict__ W2,
    const float* __restrict__ bias, const float* __restrict__ Res,
    float* __restrict__ out, int ldW, int ldOut) {
  __shared__ float Ws[128 * 128];
  __shared__ float As[64 * 128];
  gemm_body<TWOPH, RELU, HASRES>(A1, W1, A2, W2, bias, Res, out, ldW, ldOut,
                                 blockIdx.x * 64, blockIdx.y * 128, Ws, As);
}

// msg pair in one dispatch: y=0 -> A@Wtop -> outA ; y=1 -> A@Wbot+bias -> outB
__global__ __launch_bounds__(256) void msg_pair(
    const float* __restrict__ A, const float* __restrict__ Wtop,
    const float* __restrict__ Wbot, const float* __restrict__ bias,
    float* __restrict__ outA, float* __restrict__ outB) {
  __shared__ float Ws[128 * 128];
  __shared__ float As[64 * 128];
  const int y = blockIdx.y;
  gemm_body<0, 0, 0>(A, y ? Wbot : Wtop, nullptr, nullptr,
                     y ? bias : nullptr, nullptr, y ? outB : outA,
                     HID, HID, blockIdx.x * 64, 0, Ws, As);
}

// ---------------- fused message + mean-aggregation ----------------
// agg[j] = inv_deg(j) * sum_{i in in(j)} relu(A[i] + B[j])   (B already has bias)
__global__ __launch_bounds__(128) void agg_kernel(const float* __restrict__ Abuf,
                                                  const float* __restrict__ Bbuf,
                                                  const int* __restrict__ row_ptr,
                                                  const int* __restrict__ col,
                                                  float* __restrict__ agg) {
  int j = blockIdx.x;
  int c = threadIdx.x;
  float bj = Bbuf[(size_t)j * HID + c];
  int s = row_ptr[j], e = row_ptr[j + 1];
  float acc = 0.f;
  int p = s;
  for (; p + 4 <= e; p += 4) {
    int i0 = col[p], i1 = col[p+1], i2 = col[p+2], i3 = col[p+3];
    float v0 = Abuf[(size_t)i0 * HID + c];
    float v1 = Abuf[(size_t)i1 * HID + c];
    float v2 = Abuf[(size_t)i2 * HID + c];
    float v3 = Abuf[(size_t)i3 * HID + c];
    acc += fmaxf(v0 + bj, 0.f) + fmaxf(v1 + bj, 0.f)
         + fmaxf(v2 + bj, 0.f) + fmaxf(v3 + bj, 0.f);
  }
  for (; p < e; p++) {
    int i = col[p];
    acc += fmaxf(Abuf[(size_t)i * HID + c] + bj, 0.f);
  }
  float deg = (float)(e - s);
  float inv = 1.0f / fmaxf(deg, 1.0f);
  agg[(size_t)j * HID + c] = acc * inv;
}

extern "C" void kernel_launch(void* const* d_in, const int* in_sizes, int n_in,
                              void* d_out, int out_size, void* d_ws, size_t ws_size,
                              hipStream_t stream) {
  (void)in_sizes; (void)n_in; (void)out_size; (void)ws_size;
  const float* x       = (const float*)d_in[0];
  const float* pos     = (const float*)d_in[1];
  const float* enc_w0  = (const float*)d_in[3];
  const float* enc_b0  = (const float*)d_in[4];
  const float* enc_w1  = (const float*)d_in[5];
  const float* enc_b1  = (const float*)d_in[6];
  const float* msg_w   = (const float*)d_in[7];
  const float* msg_b   = (const float*)d_in[8];
  const float* upd_w   = (const float*)d_in[9];
  const float* upd_b   = (const float*)d_in[10];
  const float* proj_w0 = (const float*)d_in[11];
  const float* proj_b0 = (const float*)d_in[12];
  const float* proj_w1 = (const float*)d_in[13];
  const float* proj_b1 = (const float*)d_in[14];

  char* ws = (char*)d_ws;
  size_t off = 0;
  auto alloc = [&](size_t bytes) -> void* {
    void* p = ws + off;
    off += (bytes + 255) & ~(size_t)255;
    return p;
  };
  int*   nbr     = (int*)alloc((size_t)EE * 4);
  int*   cnt     = (int*)alloc((size_t)BN * 4);
  int*   fill    = (int*)alloc((size_t)BN * 4);
  int*   row_ptr = (int*)alloc((size_t)(BN + 1) * 4);
  int*   col     = (int*)alloc((size_t)EE * 4);
  float* h_a     = (float*)alloc((size_t)BN * HID * 4);
  float* h_b     = (float*)alloc((size_t)BN * HID * 4);
  float* bufA    = (float*)alloc((size_t)BN * HID * 4);
  float* bufB    = (float*)alloc((size_t)BN * HID * 4);
  float* bufAgg  = (float*)alloc((size_t)BN * HID * 4);
  float* out     = (float*)d_out;
  float* hOut    = out + (size_t)BN * PROJ_D;   // final h written here directly

  // cnt and fill are contiguous -> one memset
  hipMemsetAsync(cnt, 0, (size_t)BN * 4 * 2, stream);

  knn_kernel<<<BN / QPB, 1024, 0, stream>>>(pos, nbr);
  count_kernel<<<EE / 256, 256, 0, stream>>>(nbr, cnt);
  scan_kernel<<<1, 256, 0, stream>>>(cnt, row_ptr);
  fill_kernel<<<EE / 256, 256, 0, stream>>>(nbr, row_ptr, fill, col);

  enc0_kernel<<<BN * 32 / 256, 256, 0, stream>>>(x, enc_w0, enc_b0, bufA);
  gemmW<0,1,0><<<dim3(BN / 64, 1), 256, 0, stream>>>(
      bufA, enc_w1, nullptr, nullptr, enc_b1, nullptr, h_a, HID, HID);

  float* hc = h_a;
  float* hn = h_b;
  for (int i = 0; i < 3; i++) {
    const float* Wm = msg_w + (size_t)i * 256 * HID;
    msg_pair<<<dim3(BN / 64, 2), 256, 0, stream>>>(
        hc, Wm, Wm + 128 * HID, msg_b + (size_t)i * HID, bufA, bufB);
    agg_kernel<<<BN, 128, 0, stream>>>(bufA, bufB, row_ptr, col, bufAgg);
    const float* Wu = upd_w + (size_t)i * 256 * HID;
    float* target = (i == 2) ? hOut : hn;
    gemmW<1,1,1><<<dim3(BN / 64, 1), 256, 0, stream>>>(
        hc, Wu, bufAgg, Wu + 128 * HID, upd_b + (size_t)i * HID, hc, target, HID, HID);
    hn = hc; hc = target;
  }

  gemmW<0,1,0><<<dim3(BN / 64, 1), 256, 0, stream>>>(
      hc, proj_w0, nullptr, nullptr, proj_b0, nullptr, bufA, HID, HID);
  gemmW<0,0,0><<<dim3(BN / 64, 2), 256, 0, stream>>>(
      bufA, proj_w1, nullptr, nullptr, proj_b1, nullptr, out, PROJ_D, PROJ_D);
}